// Round 1
// baseline (165.936 us; speedup 1.0000x reference)
//
#include <hip/hip_runtime.h>
#include <hip/hip_bf16.h>

#define T_TOK 2048
#define H_DIM 768
#define E_NUM 16
#define F_DIM 768
#define TWOF 1536
#define TOPK 4
#define NASSIGN (T_TOK * TOPK) /* 8192 */
#define BM 64
#define BK 64
#define BNF 64
#define MAXTILE (T_TOK / BM) /* 32 */

typedef __bf16 bf16x8 __attribute__((ext_vector_type(8)));
typedef unsigned short us8 __attribute__((ext_vector_type(8)));
typedef float f32x4 __attribute__((ext_vector_type(4)));

__device__ __forceinline__ unsigned short f2bf(float f) {
  unsigned u = __float_as_uint(f);
  u += 0x7FFF + ((u >> 16) & 1);
  return (unsigned short)(u >> 16);
}

// ---------------- 1. router: logits, top-4, softmax ----------------
__global__ __launch_bounds__(64)
void router_kernel(const float* __restrict__ x, const float* __restrict__ rw,
                   const float* __restrict__ rb, float* __restrict__ scores,
                   int* __restrict__ tk_idx, float* __restrict__ tk_w) {
  const int t = blockIdx.x;
  const int lane = threadIdx.x;
  const int e = lane & 15, q = lane >> 4;
  const float* xr = x + (size_t)t * H_DIM + q * 192;
  const float* wr = rw + (size_t)e * H_DIM + q * 192;
  double acc = 0.0;
  #pragma unroll 8
  for (int i = 0; i < 192; ++i) acc += (double)xr[i] * (double)wr[i];
  acc += __shfl_xor(acc, 16, 64);
  acc += __shfl_xor(acc, 32, 64);
  __shared__ float lg[16], sc[16];
  if (lane < 16) { lg[lane] = (float)acc + rb[lane]; sc[lane] = 0.0f; }
  __syncthreads();
  if (lane == 0) {
    float v[16];
    #pragma unroll
    for (int i = 0; i < 16; ++i) v[i] = lg[i];
    int idx[TOPK]; float val[TOPK];
    for (int k = 0; k < TOPK; ++k) {
      float best = -3.4e38f; int bi = 0;
      for (int i = 0; i < 16; ++i)
        if (v[i] > best) { best = v[i]; bi = i; }
      idx[k] = bi; val[k] = best; v[bi] = -3.4e38f;
    }
    float s = 0.0f, ev[TOPK];
    for (int k = 0; k < TOPK; ++k) { ev[k] = expf(val[k] - val[0]); s += ev[k]; }
    for (int k = 0; k < TOPK; ++k) {
      float wgt = ev[k] / s;
      sc[idx[k]] = wgt;
      tk_idx[t * TOPK + k] = idx[k];
      tk_w[t * TOPK + k] = wgt;
    }
  }
  __syncthreads();
  if (lane < 16) scores[(size_t)t * 16 + lane] = sc[lane];
}

// ---------------- 2. deterministic group-by-expert ----------------
__global__ __launch_bounds__(256)
void group_kernel(const int* __restrict__ tk_idx, const float* __restrict__ tk_w,
                  int* __restrict__ counts, int* __restrict__ offs,
                  int* __restrict__ tmap, float* __restrict__ wgrp) {
  __shared__ int hist[256][16];
  __shared__ int cnt[16], eoff[16];
  const int tid = threadIdx.x;
  int loc[16];
  #pragma unroll
  for (int e = 0; e < 16; ++e) loc[e] = 0;
  const int base = tid * 32;
  int eid[32];
  for (int i = 0; i < 32; ++i) { int e = tk_idx[base + i]; eid[i] = e; loc[e]++; }
  #pragma unroll
  for (int e = 0; e < 16; ++e) hist[tid][e] = loc[e];
  __syncthreads();
  if (tid < 16) {
    int s = 0;
    for (int j = 0; j < 256; ++j) { int c = hist[j][tid]; hist[j][tid] = s; s += c; }
    cnt[tid] = s;
  }
  __syncthreads();
  if (tid == 0) {
    int s = 0;
    for (int e = 0; e < 16; ++e) { eoff[e] = s; s += cnt[e]; }
  }
  __syncthreads();
  if (tid < 16) { counts[tid] = cnt[tid]; offs[tid] = eoff[tid]; }
  int run[16];
  #pragma unroll
  for (int e = 0; e < 16; ++e) run[e] = hist[tid][e];
  for (int i = 0; i < 32; ++i) {
    int e = eid[i];
    int slot = eoff[e] + run[e]++;
    tmap[slot] = base + i;        // assignment id = t*4 + k
    wgrp[slot] = tk_w[base + i];
  }
}

// ---------------- 3. grouped GEMM1: gate_up + GLU -> act (bf16) ----------------
__global__ __launch_bounds__(256)
void gemm1_kernel(const float* __restrict__ x, const float* __restrict__ gup,
                  const float* __restrict__ gupb,
                  const int* __restrict__ counts, const int* __restrict__ offs,
                  const int* __restrict__ tmap,
                  unsigned short* __restrict__ act) {
  const int e = blockIdx.y >> 5;
  const int tile = blockIdx.y & 31;
  const int count = counts[e];
  if (tile * BM >= count) return;
  const int off = offs[e];
  const int f0 = blockIdx.x * BNF;
  const int tid = threadIdx.x;
  const int wave = tid >> 6, lane = tid & 63;

  __shared__ unsigned short lA[BM * BK];
  __shared__ unsigned short lBg[BNF * BK];
  __shared__ unsigned short lBu[BNF * BK];

  const int k8 = tid & 7, sm0 = tid >> 3; // staging coords
  int tok0, tok1;
  {
    int mm0 = tile * BM + sm0;      if (mm0 >= count) mm0 = count - 1;
    int mm1 = tile * BM + sm0 + 32; if (mm1 >= count) mm1 = count - 1;
    tok0 = tmap[off + mm0] >> 2;
    tok1 = tmap[off + mm1] >> 2;
  }
  const int bn = tid & 63, bkk = tid >> 6;
  const float* gbase = gup + (size_t)(e * H_DIM) * TWOF + 2 * (f0 + bn);

  f32x4 accg[4] = {{0,0,0,0},{0,0,0,0},{0,0,0,0},{0,0,0,0}};
  f32x4 accu[4] = {{0,0,0,0},{0,0,0,0},{0,0,0,0},{0,0,0,0}};

  for (int kt = 0; kt < 12; ++kt) {
    const int kk0 = kt * BK;
    { // stage A (tokens x K), fp32 -> bf16, swizzled
      const float* xp0 = x + (size_t)tok0 * H_DIM + kk0 + k8 * 8;
      const float* xp1 = x + (size_t)tok1 * H_DIM + kk0 + k8 * 8;
      f32x4 a0 = *(const f32x4*)xp0;
      f32x4 a1 = *(const f32x4*)(xp0 + 4);
      f32x4 b0 = *(const f32x4*)xp1;
      f32x4 b1 = *(const f32x4*)(xp1 + 4);
      us8 o0, o1;
      #pragma unroll
      for (int j = 0; j < 4; ++j) {
        o0[j] = f2bf(a0[j]); o0[4 + j] = f2bf(a1[j]);
        o1[j] = f2bf(b0[j]); o1[4 + j] = f2bf(b1[j]);
      }
      *(us8*)&lA[sm0 * BK + 8 * (k8 ^ (sm0 & 7))] = o0;
      const int sm1 = sm0 + 32;
      *(us8*)&lA[sm1 * BK + 8 * (k8 ^ (sm1 & 7))] = o1;
    }
    { // stage B gate (even cols) + up (odd cols), [n][k] layout
      const float* wp = gbase + (size_t)(kk0 + bkk * 16) * TWOF;
      unsigned short gv[16], uv[16];
      #pragma unroll
      for (int r = 0; r < 16; ++r) {
        const float* p = wp + (size_t)r * TWOF;
        gv[r] = f2bf(p[0]); uv[r] = f2bf(p[1]);
      }
      us8 w0, w1, w2, w3;
      #pragma unroll
      for (int j = 0; j < 8; ++j) { w0[j]=gv[j]; w1[j]=gv[8+j]; w2[j]=uv[j]; w3[j]=uv[8+j]; }
      const int nx = bn & 7;
      *(us8*)&lBg[bn * BK + 8 * ((bkk * 2 + 0) ^ nx)] = w0;
      *(us8*)&lBg[bn * BK + 8 * ((bkk * 2 + 1) ^ nx)] = w1;
      *(us8*)&lBu[bn * BK + 8 * ((bkk * 2 + 0) ^ nx)] = w2;
      *(us8*)&lBu[bn * BK + 8 * ((bkk * 2 + 1) ^ nx)] = w3;
    }
    __syncthreads();
    const int ml = lane & 15, lh = lane >> 4;
    #pragma unroll
    for (int sub = 0; sub < 2; ++sub) {
      const int slot = sub * 4 + lh;
      const int arow = wave * 16 + ml;
      bf16x8 af = __builtin_bit_cast(bf16x8, *(const us8*)&lA[arow * BK + 8 * (slot ^ (arow & 7))]);
      #pragma unroll
      for (int nf = 0; nf < 4; ++nf) {
        const int brow = nf * 16 + ml;
        bf16x8 bg = __builtin_bit_cast(bf16x8, *(const us8*)&lBg[brow * BK + 8 * (slot ^ (brow & 7))]);
        bf16x8 bu = __builtin_bit_cast(bf16x8, *(const us8*)&lBu[brow * BK + 8 * (slot ^ (brow & 7))]);
        accg[nf] = __builtin_amdgcn_mfma_f32_16x16x32_bf16(af, bg, accg[nf], 0, 0, 0);
        accu[nf] = __builtin_amdgcn_mfma_f32_16x16x32_bf16(af, bu, accu[nf], 0, 0, 0);
      }
    }
    __syncthreads();
  }
  const int ml = lane & 15, lh = lane >> 4;
  #pragma unroll
  for (int nf = 0; nf < 4; ++nf) {
    const int fc = f0 + nf * 16 + ml;
    const float bg = gupb[(size_t)e * TWOF + 2 * fc];
    const float bu = gupb[(size_t)e * TWOF + 2 * fc + 1];
    #pragma unroll
    for (int r = 0; r < 4; ++r) {
      const int m = tile * BM + wave * 16 + 4 * lh + r;
      if (m < count) {
        float g = accg[nf][r] + bg;
        float u = accu[nf][r] + bu;
        g = fminf(g, 7.0f);
        u = fminf(fmaxf(u, -7.0f), 7.0f);
        const float glu = g / (1.0f + expf(-1.702f * g));
        act[(size_t)(off + m) * F_DIM + fc] = f2bf((u + 1.0f) * glu);
      }
    }
  }
}

// ---------------- 4. grouped GEMM2: act @ down + bias, x route weight ----------------
__global__ __launch_bounds__(256)
void gemm2_kernel(const unsigned short* __restrict__ act, const float* __restrict__ dwn,
                  const float* __restrict__ dwnb,
                  const int* __restrict__ counts, const int* __restrict__ offs,
                  const int* __restrict__ tmap, const float* __restrict__ wgrp,
                  float* __restrict__ partial) {
  const int e = blockIdx.y >> 5;
  const int tile = blockIdx.y & 31;
  const int count = counts[e];
  if (tile * BM >= count) return;
  const int off = offs[e];
  const int h0 = blockIdx.x * 64;
  const int tid = threadIdx.x;
  const int wave = tid >> 6, lane = tid & 63;

  __shared__ unsigned short lA[BM * BK];
  __shared__ unsigned short lB[64 * BK];

  const int k8 = tid & 7, sm0 = tid >> 3;
  const int row0 = off + tile * BM + sm0;  // slack rows allocated in act
  const int row1 = row0 + 32;
  const int bn = tid & 63, bkk = tid >> 6;
  const float* dbase = dwn + (size_t)(e * F_DIM) * H_DIM + h0 + bn;

  f32x4 acc[4] = {{0,0,0,0},{0,0,0,0},{0,0,0,0},{0,0,0,0}};

  for (int kt = 0; kt < 12; ++kt) {
    const int kk0 = kt * BK;
    {
      us8 o0 = *(const us8*)&act[(size_t)row0 * F_DIM + kk0 + k8 * 8];
      us8 o1 = *(const us8*)&act[(size_t)row1 * F_DIM + kk0 + k8 * 8];
      *(us8*)&lA[sm0 * BK + 8 * (k8 ^ (sm0 & 7))] = o0;
      const int sm1 = sm0 + 32;
      *(us8*)&lA[sm1 * BK + 8 * (k8 ^ (sm1 & 7))] = o1;
    }
    {
      const float* wp = dbase + (size_t)(kk0 + bkk * 16) * H_DIM;
      unsigned short bv[16];
      #pragma unroll
      for (int r = 0; r < 16; ++r) bv[r] = f2bf(wp[(size_t)r * H_DIM]);
      us8 w0, w1;
      #pragma unroll
      for (int j = 0; j < 8; ++j) { w0[j] = bv[j]; w1[j] = bv[8 + j]; }
      const int nx = bn & 7;
      *(us8*)&lB[bn * BK + 8 * ((bkk * 2 + 0) ^ nx)] = w0;
      *(us8*)&lB[bn * BK + 8 * ((bkk * 2 + 1) ^ nx)] = w1;
    }
    __syncthreads();
    const int ml = lane & 15, lh = lane >> 4;
    #pragma unroll
    for (int sub = 0; sub < 2; ++sub) {
      const int slot = sub * 4 + lh;
      const int arow = wave * 16 + ml;
      bf16x8 af = __builtin_bit_cast(bf16x8, *(const us8*)&lA[arow * BK + 8 * (slot ^ (arow & 7))]);
      #pragma unroll
      for (int nf = 0; nf < 4; ++nf) {
        const int brow = nf * 16 + ml;
        bf16x8 bfv = __builtin_bit_cast(bf16x8, *(const us8*)&lB[brow * BK + 8 * (slot ^ (brow & 7))]);
        acc[nf] = __builtin_amdgcn_mfma_f32_16x16x32_bf16(af, bfv, acc[nf], 0, 0, 0);
      }
    }
    __syncthreads();
  }
  const int ml = lane & 15, lh = lane >> 4;
  #pragma unroll
  for (int nf = 0; nf < 4; ++nf) {
    const int hc = h0 + nf * 16 + ml;
    const float bias = dwnb[(size_t)e * H_DIM + hc];
    #pragma unroll
    for (int r = 0; r < 4; ++r) {
      const int m = tile * BM + wave * 16 + 4 * lh + r;
      if (m < count) {
        const int slot = off + m;
        partial[(size_t)tmap[slot] * H_DIM + hc] = wgrp[slot] * (acc[nf][r] + bias);
      }
    }
  }
}

// ---------------- 5. reduce partials over k ----------------
__global__ __launch_bounds__(256)
void reduce_kernel(const float* __restrict__ partial, float* __restrict__ out) {
  const int idx = blockIdx.x * 256 + threadIdx.x;
  const int v = idx * 4;
  const int t = v / H_DIM;
  const int h = v - t * H_DIM;
  f32x4 s = {0, 0, 0, 0};
  #pragma unroll
  for (int k = 0; k < 4; ++k) {
    const f32x4 p = *(const f32x4*)&partial[(size_t)(t * 4 + k) * H_DIM + h];
    s += p;
  }
  *(f32x4*)&out[v] = s;
}

extern "C" void kernel_launch(void* const* d_in, const int* in_sizes, int n_in,
                              void* d_out, int out_size, void* d_ws, size_t ws_size,
                              hipStream_t stream) {
  const float* x    = (const float*)d_in[0];
  const float* rw   = (const float*)d_in[1];
  const float* rb   = (const float*)d_in[2];
  const float* gup  = (const float*)d_in[3];
  const float* gupb = (const float*)d_in[4];
  const float* dwn  = (const float*)d_in[5];
  const float* dwnb = (const float*)d_in[6];
  float* out = (float*)d_out;
  float* scores = out + (size_t)T_TOK * H_DIM;

  char* w = (char*)d_ws;
  int*   tk_idx = (int*)w;            w += NASSIGN * 4;
  float* tk_w   = (float*)w;          w += NASSIGN * 4;
  int*   counts = (int*)w;            w += 64;
  int*   offs   = (int*)w;            w += 64;
  int*   tmap   = (int*)w;            w += (NASSIGN + 128) * 4;
  float* wgrp   = (float*)w;          w += (NASSIGN + 128) * 4;
  unsigned short* act = (unsigned short*)w; w += (size_t)(NASSIGN + 128) * F_DIM * 2;
  float* partial = (float*)w;         w += (size_t)NASSIGN * H_DIM * 4;

  router_kernel<<<T_TOK, 64, 0, stream>>>(x, rw, rb, scores, tk_idx, tk_w);
  group_kernel<<<1, 256, 0, stream>>>(tk_idx, tk_w, counts, offs, tmap, wgrp);
  gemm1_kernel<<<dim3(F_DIM / BNF, E_NUM * MAXTILE), 256, 0, stream>>>(
      x, gup, gupb, counts, offs, tmap, act);
  gemm2_kernel<<<dim3(H_DIM / 64, E_NUM * MAXTILE), 256, 0, stream>>>(
      act, dwn, dwnb, counts, offs, tmap, wgrp, partial);
  reduce_kernel<<<(T_TOK * H_DIM / 4) / 256, 256, 0, stream>>>(partial, out);
}

// Round 2
// 158.825 us; speedup vs baseline: 1.0448x; 1.0448x over previous
//
#include <hip/hip_runtime.h>
#include <hip/hip_bf16.h>

#define T_TOK 2048
#define H_DIM 768
#define E_NUM 16
#define F_DIM 768
#define TWOF 1536
#define TOPK 4
#define NASSIGN 8192
#define BM 128
#define BK 64
#define BN 64
#define KT 12            /* 768/64 k-tiles */
#define NTILE 80         /* padded slots / BM = 10240/128 */
#define NSLOTP (NTILE * BM)
#define MAXT1 10         /* max tiles per expert (count <= 1280) */
#define CHUNK (BM * BK)  /* 8192 halfwords per A/act chunk */
#define WTILE (BN * BK)  /* 4096 halfwords per weight tile */

typedef __bf16 bf16x8 __attribute__((ext_vector_type(8)));
typedef unsigned short us8 __attribute__((ext_vector_type(8)));
typedef float f32x4 __attribute__((ext_vector_type(4)));

__device__ __forceinline__ unsigned short f2bf(float f) {
  unsigned u = __float_as_uint(f);
  u += 0x7FFF + ((u >> 16) & 1);
  return (unsigned short)(u >> 16);
}

__device__ __forceinline__ void gl_lds16(const unsigned short* g, unsigned short* l) {
  __builtin_amdgcn_global_load_lds(
      (const __attribute__((address_space(1))) unsigned int*)g,
      (__attribute__((address_space(3))) unsigned int*)l, 16, 0, 0);
}

// ---------------- 1. router: logits (fp64 acc), top-4, softmax ----------------
__global__ __launch_bounds__(64)
void router_kernel(const float* __restrict__ x, const float* __restrict__ rw,
                   const float* __restrict__ rb, float* __restrict__ scores,
                   int* __restrict__ tk_idx, float* __restrict__ tk_w) {
  const int t = blockIdx.x;
  const int lane = threadIdx.x;
  const int e = lane & 15, q = lane >> 4;
  const float* xr = x + (size_t)t * H_DIM + q * 192;
  const float* wr = rw + (size_t)e * H_DIM + q * 192;
  double a0 = 0.0, a1 = 0.0, a2 = 0.0, a3 = 0.0;
  #pragma unroll 4
  for (int i = 0; i < 192; i += 4) {
    a0 += (double)xr[i + 0] * (double)wr[i + 0];
    a1 += (double)xr[i + 1] * (double)wr[i + 1];
    a2 += (double)xr[i + 2] * (double)wr[i + 2];
    a3 += (double)xr[i + 3] * (double)wr[i + 3];
  }
  double acc = (a0 + a1) + (a2 + a3);
  acc += __shfl_xor(acc, 16, 64);
  acc += __shfl_xor(acc, 32, 64);
  __shared__ float lg[16], sc[16];
  if (lane < 16) { lg[lane] = (float)acc + rb[lane]; sc[lane] = 0.0f; }
  __syncthreads();
  if (lane == 0) {
    float v[16];
    #pragma unroll
    for (int i = 0; i < 16; ++i) v[i] = lg[i];
    int idx[TOPK]; float val[TOPK];
    for (int k = 0; k < TOPK; ++k) {
      float best = -3.4e38f; int bi = 0;
      for (int i = 0; i < 16; ++i)
        if (v[i] > best) { best = v[i]; bi = i; }
      idx[k] = bi; val[k] = best; v[bi] = -3.4e38f;
    }
    float s = 0.0f, ev[TOPK];
    for (int k = 0; k < TOPK; ++k) { ev[k] = expf(val[k] - val[0]); s += ev[k]; }
    for (int k = 0; k < TOPK; ++k) {
      float wgt = ev[k] / s;
      sc[idx[k]] = wgt;
      tk_idx[t * TOPK + k] = idx[k];
      tk_w[t * TOPK + k] = wgt;
    }
  }
  __syncthreads();
  if (lane < 16) scores[(size_t)t * 16 + lane] = sc[lane];
}

// ---------------- 2. deterministic group-by-expert (padded to BM) ----------------
__global__ __launch_bounds__(256)
void group_kernel(const int* __restrict__ tk_idx, const float* __restrict__ tk_w,
                  int* __restrict__ counts, int* __restrict__ offs,
                  int* __restrict__ tmap, float* __restrict__ wgrp) {
  __shared__ int hist[256][16];
  __shared__ int cnt[16], eoff[16];
  const int tid = threadIdx.x;
  for (int i = tid; i < NSLOTP; i += 256) { tmap[i] = 0; wgrp[i] = 0.0f; }
  int loc[16];
  #pragma unroll
  for (int e = 0; e < 16; ++e) loc[e] = 0;
  const int base = tid * 32;
  int eid[32];
  for (int i = 0; i < 32; ++i) { int e = tk_idx[base + i]; eid[i] = e; loc[e]++; }
  #pragma unroll
  for (int e = 0; e < 16; ++e) hist[tid][e] = loc[e];
  __syncthreads();
  if (tid < 16) {
    int s = 0;
    for (int j = 0; j < 256; ++j) { int c = hist[j][tid]; hist[j][tid] = s; s += c; }
    cnt[tid] = s;
  }
  __syncthreads();
  if (tid == 0) {
    int s = 0;
    for (int e = 0; e < 16; ++e) { eoff[e] = s; s += (cnt[e] + BM - 1) / BM * BM; }
  }
  __syncthreads();
  if (tid < 16) { counts[tid] = cnt[tid]; offs[tid] = eoff[tid]; }
  int run[16];
  #pragma unroll
  for (int e = 0; e < 16; ++e) run[e] = hist[tid][e];
  for (int i = 0; i < 32; ++i) {
    int e = eid[i];
    int slot = eoff[e] + run[e]++;
    tmap[slot] = base + i;        // assignment id = t*4 + k
    wgrp[slot] = tk_w[base + i];
  }
}

// ---------------- 3. weight convert: fp32 -> bf16, transposed [n][k], pre-swizzled ----------------
// z < 16: gate_up expert z -> gw (even cols) + uw (odd cols); z >= 16: down expert z-16 -> dw
__global__ __launch_bounds__(256)
void convert_w_kernel(const float* __restrict__ gup, const float* __restrict__ dwn,
                      unsigned short* __restrict__ gw, unsigned short* __restrict__ uw,
                      unsigned short* __restrict__ dw) {
  const int ft = blockIdx.x, kt = blockIdx.y, z = blockIdx.z;
  const int tid = threadIdx.x;
  __shared__ unsigned short t0[WTILE], t1[WTILE];
  if (z < 16) {
    const int e = z;
    const int hr = tid >> 2;            // local k row (h)
    const int c0 = (tid & 3) * 32;      // col within 128-float chunk
    const float* src = gup + ((size_t)(e * H_DIM + kt * 64 + hr)) * TWOF + ft * 128 + c0;
    float v[32];
    #pragma unroll
    for (int i = 0; i < 8; ++i) {
      f32x4 qv = *(const f32x4*)(src + 4 * i);
      v[4*i+0] = qv[0]; v[4*i+1] = qv[1]; v[4*i+2] = qv[2]; v[4*i+3] = qv[3];
    }
    const int k8 = hr >> 3, j = hr & 7;
    #pragma unroll
    for (int i = 0; i < 16; ++i) {
      const int n = (c0 >> 1) + i;      // local f col
      const int idx = n * BK + 8 * (k8 ^ (n & 7)) + j;
      t0[idx] = f2bf(v[2*i]);           // gate (even)
      t1[idx] = f2bf(v[2*i+1]);         // up (odd)
    }
    __syncthreads();
    unsigned short* gb = gw + (((size_t)e * KT + kt) * 12 + ft) * WTILE;
    unsigned short* ub = uw + (((size_t)e * KT + kt) * 12 + ft) * WTILE;
    #pragma unroll
    for (int i = 0; i < 2; ++i) {
      *(us8*)&gb[(i*256+tid)*8] = *(const us8*)&t0[(i*256+tid)*8];
      *(us8*)&ub[(i*256+tid)*8] = *(const us8*)&t1[(i*256+tid)*8];
    }
  } else {
    const int e = z - 16;
    const int fr = tid >> 2;            // local k row (f)
    const int c0 = (tid & 3) * 16;      // local h col
    const float* src = dwn + ((size_t)(e * F_DIM + kt * 64 + fr)) * H_DIM + ft * 64 + c0;
    float v[16];
    #pragma unroll
    for (int i = 0; i < 4; ++i) {
      f32x4 qv = *(const f32x4*)(src + 4 * i);
      v[4*i+0] = qv[0]; v[4*i+1] = qv[1]; v[4*i+2] = qv[2]; v[4*i+3] = qv[3];
    }
    const int k8 = fr >> 3, j = fr & 7;
    #pragma unroll
    for (int i = 0; i < 16; ++i) {
      const int n = c0 + i;
      t0[n * BK + 8 * (k8 ^ (n & 7)) + j] = f2bf(v[i]);
    }
    __syncthreads();
    unsigned short* db = dw + (((size_t)e * KT + kt) * 12 + ft) * WTILE;
    #pragma unroll
    for (int i = 0; i < 2; ++i)
      *(us8*)&db[(i*256+tid)*8] = *(const us8*)&t0[(i*256+tid)*8];
  }
}

// ---------------- 4. gather+convert x -> xg (group order, swizzled chunks) ----------------
__global__ __launch_bounds__(256)
void convert_x_kernel(const float* __restrict__ x, const int* __restrict__ tmap,
                      unsigned short* __restrict__ xg) {
  const int tile = blockIdx.x;     // 0..NTILE-1
  const int kt = blockIdx.y;       // 0..11
  const int tid = threadIdx.x;
  const int r = tid >> 1;          // 128 rows, 2 threads/row
  const int c0 = (tid & 1) * 32;
  const int tok = tmap[tile * BM + r] >> 2;
  const float* src = x + (size_t)tok * H_DIM + kt * 64 + c0;
  unsigned short* dst = xg + ((size_t)tile * KT + kt) * CHUNK + r * BK;
  #pragma unroll
  for (int qq = 0; qq < 4; ++qq) {
    f32x4 a = *(const f32x4*)(src + 8 * qq);
    f32x4 b = *(const f32x4*)(src + 8 * qq + 4);
    us8 o;
    #pragma unroll
    for (int j = 0; j < 4; ++j) { o[j] = f2bf(a[j]); o[4+j] = f2bf(b[j]); }
    const int k8 = (c0 >> 3) + qq;
    *(us8*)&dst[8 * (k8 ^ (r & 7))] = o;
  }
}

// ---------------- 5. grouped GEMM1: xg @ [gate|up] + GLU -> act (swizzled chunks) ----------------
__global__ __launch_bounds__(256)
void gemm1_kernel(const unsigned short* __restrict__ xg, const unsigned short* __restrict__ gw,
                  const unsigned short* __restrict__ uw, const float* __restrict__ gupb,
                  const int* __restrict__ counts, const int* __restrict__ offs,
                  unsigned short* __restrict__ act) {
  const int e = blockIdx.y / MAXT1;
  const int tile = blockIdx.y % MAXT1;
  const int count = counts[e];
  if (tile * BM >= count) return;
  const int tileg = (offs[e] >> 7) + tile;
  const int ft = blockIdx.x;
  const int tid = threadIdx.x;
  const int wv = tid >> 6, lane = tid & 63;
  const int ml = lane & 15, lh = lane >> 4;

  __shared__ unsigned short lA[CHUNK];   // 16KB
  __shared__ unsigned short lBg[WTILE];  // 8KB
  __shared__ unsigned short lBu[WTILE];  // 8KB

  const unsigned short* ab = xg + (size_t)tileg * KT * CHUNK;
  const unsigned short* gb = gw + ((size_t)e * KT * 12 + ft) * WTILE;
  const unsigned short* ub = uw + ((size_t)e * KT * 12 + ft) * WTILE;

  f32x4 accg[2][4] = {};
  f32x4 accu[2][4] = {};

  for (int kt = 0; kt < KT; ++kt) {
    const unsigned short* as = ab + kt * CHUNK;
    const unsigned short* gs = gb + (size_t)kt * 12 * WTILE;
    const unsigned short* us = ub + (size_t)kt * 12 * WTILE;
    #pragma unroll
    for (int i = 0; i < 4; ++i) gl_lds16(as + (i*256+tid)*8, &lA[(i*256+tid)*8]);
    #pragma unroll
    for (int i = 0; i < 2; ++i) gl_lds16(gs + (i*256+tid)*8, &lBg[(i*256+tid)*8]);
    #pragma unroll
    for (int i = 0; i < 2; ++i) gl_lds16(us + (i*256+tid)*8, &lBu[(i*256+tid)*8]);
    __syncthreads();
    #pragma unroll
    for (int ks = 0; ks < 2; ++ks) {
      const int slot = ks * 4 + lh;
      bf16x8 af0, af1;
      {
        const int ar0 = wv * 32 + ml;
        const int ar1 = wv * 32 + 16 + ml;
        af0 = __builtin_bit_cast(bf16x8, *(const us8*)&lA[ar0 * BK + 8 * (slot ^ (ar0 & 7))]);
        af1 = __builtin_bit_cast(bf16x8, *(const us8*)&lA[ar1 * BK + 8 * (slot ^ (ar1 & 7))]);
      }
      #pragma unroll
      for (int nf = 0; nf < 4; ++nf) {
        const int br = nf * 16 + ml;
        bf16x8 bg = __builtin_bit_cast(bf16x8, *(const us8*)&lBg[br * BK + 8 * (slot ^ (br & 7))]);
        bf16x8 bu = __builtin_bit_cast(bf16x8, *(const us8*)&lBu[br * BK + 8 * (slot ^ (br & 7))]);
        accg[0][nf] = __builtin_amdgcn_mfma_f32_16x16x32_bf16(af0, bg, accg[0][nf], 0, 0, 0);
        accg[1][nf] = __builtin_amdgcn_mfma_f32_16x16x32_bf16(af1, bg, accg[1][nf], 0, 0, 0);
        accu[0][nf] = __builtin_amdgcn_mfma_f32_16x16x32_bf16(af0, bu, accu[0][nf], 0, 0, 0);
        accu[1][nf] = __builtin_amdgcn_mfma_f32_16x16x32_bf16(af1, bu, accu[1][nf], 0, 0, 0);
      }
    }
    __syncthreads();
  }
  // epilogue: activation, write swizzled chunk via LDS transit
  #pragma unroll
  for (int mf = 0; mf < 2; ++mf) {
    #pragma unroll
    for (int nf = 0; nf < 4; ++nf) {
      const int col = nf * 16 + ml;
      const int fc = ft * 64 + col;
      const float bgv = gupb[(size_t)e * TWOF + 2 * fc];
      const float buv = gupb[(size_t)e * TWOF + 2 * fc + 1];
      #pragma unroll
      for (int r = 0; r < 4; ++r) {
        const int m = wv * 32 + mf * 16 + lh * 4 + r;
        float g = accg[mf][nf][r] + bgv;
        float u = accu[mf][nf][r] + buv;
        g = fminf(g, 7.0f);
        u = fminf(fmaxf(u, -7.0f), 7.0f);
        const float glu = g / (1.0f + expf(-1.702f * g));
        lA[m * BK + 8 * ((col >> 3) ^ (m & 7)) + (col & 7)] = f2bf((u + 1.0f) * glu);
      }
    }
  }
  __syncthreads();
  unsigned short* ob = act + ((size_t)tileg * KT + ft) * CHUNK;
  #pragma unroll
  for (int i = 0; i < 4; ++i)
    *(us8*)&ob[(i*256+tid)*8] = *(const us8*)&lA[(i*256+tid)*8];
}

// ---------------- 6. grouped GEMM2: act @ down + bias, x route weight -> partial ----------------
__global__ __launch_bounds__(256)
void gemm2_kernel(const unsigned short* __restrict__ act, const unsigned short* __restrict__ dw,
                  const float* __restrict__ dwnb, const int* __restrict__ counts,
                  const int* __restrict__ offs, const int* __restrict__ tmap,
                  const float* __restrict__ wgrp, float* __restrict__ partial) {
  const int e = blockIdx.y / MAXT1;
  const int tile = blockIdx.y % MAXT1;
  const int count = counts[e];
  if (tile * BM >= count) return;
  const int off = offs[e];
  const int tileg = (off >> 7) + tile;
  const int ft = blockIdx.x;  // h-tile
  const int tid = threadIdx.x;
  const int wv = tid >> 6, lane = tid & 63;
  const int ml = lane & 15, lh = lane >> 4;

  __shared__ unsigned short lA[CHUNK];
  __shared__ unsigned short lB[WTILE];

  const unsigned short* ab = act + (size_t)tileg * KT * CHUNK;
  const unsigned short* bb = dw + ((size_t)e * KT * 12 + ft) * WTILE;

  f32x4 acc[2][4] = {};

  for (int kt = 0; kt < KT; ++kt) {
    const unsigned short* as = ab + kt * CHUNK;
    const unsigned short* bs = bb + (size_t)kt * 12 * WTILE;
    #pragma unroll
    for (int i = 0; i < 4; ++i) gl_lds16(as + (i*256+tid)*8, &lA[(i*256+tid)*8]);
    #pragma unroll
    for (int i = 0; i < 2; ++i) gl_lds16(bs + (i*256+tid)*8, &lB[(i*256+tid)*8]);
    __syncthreads();
    #pragma unroll
    for (int ks = 0; ks < 2; ++ks) {
      const int slot = ks * 4 + lh;
      bf16x8 af0, af1;
      {
        const int ar0 = wv * 32 + ml;
        const int ar1 = wv * 32 + 16 + ml;
        af0 = __builtin_bit_cast(bf16x8, *(const us8*)&lA[ar0 * BK + 8 * (slot ^ (ar0 & 7))]);
        af1 = __builtin_bit_cast(bf16x8, *(const us8*)&lA[ar1 * BK + 8 * (slot ^ (ar1 & 7))]);
      }
      #pragma unroll
      for (int nf = 0; nf < 4; ++nf) {
        const int br = nf * 16 + ml;
        bf16x8 bv = __builtin_bit_cast(bf16x8, *(const us8*)&lB[br * BK + 8 * (slot ^ (br & 7))]);
        acc[0][nf] = __builtin_amdgcn_mfma_f32_16x16x32_bf16(af0, bv, acc[0][nf], 0, 0, 0);
        acc[1][nf] = __builtin_amdgcn_mfma_f32_16x16x32_bf16(af1, bv, acc[1][nf], 0, 0, 0);
      }
    }
    __syncthreads();
  }
  #pragma unroll
  for (int mf = 0; mf < 2; ++mf) {
    #pragma unroll
    for (int nf = 0; nf < 4; ++nf) {
      const int hc = ft * 64 + nf * 16 + ml;
      const float bias = dwnb[(size_t)e * H_DIM + hc];
      #pragma unroll
      for (int r = 0; r < 4; ++r) {
        const int m = tile * BM + wv * 32 + mf * 16 + lh * 4 + r;
        if (m < count) {
          const int slot = off + m;
          partial[(size_t)tmap[slot] * H_DIM + hc] = wgrp[slot] * (acc[mf][nf][r] + bias);
        }
      }
    }
  }
}

// ---------------- 7. reduce partials over k ----------------
__global__ __launch_bounds__(256)
void reduce_kernel(const float* __restrict__ partial, float* __restrict__ out) {
  const int idx = blockIdx.x * 256 + threadIdx.x;
  const int v = idx * 4;
  const int t = v / H_DIM;
  const int h = v - t * H_DIM;
  f32x4 s = {0, 0, 0, 0};
  #pragma unroll
  for (int k = 0; k < 4; ++k) {
    const f32x4 p = *(const f32x4*)&partial[(size_t)(t * 4 + k) * H_DIM + h];
    s += p;
  }
  *(f32x4*)&out[v] = s;
}

extern "C" void kernel_launch(void* const* d_in, const int* in_sizes, int n_in,
                              void* d_out, int out_size, void* d_ws, size_t ws_size,
                              hipStream_t stream) {
  const float* x    = (const float*)d_in[0];
  const float* rw   = (const float*)d_in[1];
  const float* rb   = (const float*)d_in[2];
  const float* gup  = (const float*)d_in[3];
  const float* gupb = (const float*)d_in[4];
  const float* dwn  = (const float*)d_in[5];
  const float* dwnb = (const float*)d_in[6];
  float* out = (float*)d_out;
  float* scores = out + (size_t)T_TOK * H_DIM;

  char* w = (char*)d_ws;
  int*   tk_idx = (int*)w;            w += NASSIGN * 4;
  float* tk_w   = (float*)w;          w += NASSIGN * 4;
  int*   counts = (int*)w;            w += 64;
  int*   offs   = (int*)w;            w += 64;
  int*   tmap   = (int*)w;            w += NSLOTP * 4;
  float* wgrp   = (float*)w;          w += NSLOTP * 4;
  unsigned short* gw = (unsigned short*)w; w += (size_t)E_NUM * KT * 12 * WTILE * 2;
  unsigned short* uw = (unsigned short*)w; w += (size_t)E_NUM * KT * 12 * WTILE * 2;
  unsigned short* dw = (unsigned short*)w; w += (size_t)E_NUM * KT * 12 * WTILE * 2;
  unsigned short* xg = (unsigned short*)w; w += (size_t)NTILE * KT * CHUNK * 2;
  unsigned short* act = (unsigned short*)w; w += (size_t)NTILE * KT * CHUNK * 2;
  float* partial = (float*)w;         w += (size_t)NASSIGN * H_DIM * 4;

  convert_w_kernel<<<dim3(12, 12, 32), 256, 0, stream>>>(gup, dwn, gw, uw, dw);
  router_kernel<<<T_TOK, 64, 0, stream>>>(x, rw, rb, scores, tk_idx, tk_w);
  group_kernel<<<1, 256, 0, stream>>>(tk_idx, tk_w, counts, offs, tmap, wgrp);
  convert_x_kernel<<<dim3(NTILE, KT), 256, 0, stream>>>(x, tmap, xg);
  gemm1_kernel<<<dim3(12, E_NUM * MAXT1), 256, 0, stream>>>(
      xg, gw, uw, gupb, counts, offs, act);
  gemm2_kernel<<<dim3(12, E_NUM * MAXT1), 256, 0, stream>>>(
      act, dw, dwnb, counts, offs, tmap, wgrp, partial);
  reduce_kernel<<<(T_TOK * H_DIM / 4) / 256, 256, 0, stream>>>(partial, out);
}